// Round 1
// baseline (856.600 us; speedup 1.0000x reference)
//
#include <hip/hip_runtime.h>

// 2D Haar DWT, fused single pass.
// x: [B=8, C=64, H=512, W=512] f32 -> LL,LH,HL,HH each [8,64,256,256] f32,
// concatenated flat in d_out in that order.
//
// Per 2x2 input block (a b / c d):
//   LL = 0.5(a+b+c+d)   LH = 0.5(a-b+c-d)
//   HL = 0.5(a+b-c-d)   HH = 0.5(a-b-c+d)
//
// Each thread: 2 x float4 input loads (rows 2i, 2i+1), 4 x float2 output
// stores. Memory-bound: ~1.07 GB total traffic.

__global__ __launch_bounds__(256) void haar_dwt_kernel(
    const float* __restrict__ x, float* __restrict__ out, int total) {
    // Work item t = bc*256*128 + i*128 + jv
    //   bc in [0,512)   : fused B*C image index
    //   i  in [0,256)   : output row
    //   jv in [0,128)   : float4 column group (= 2 output cols)
    const int W = 512;            // input width
    const int HW = 512 * 512;     // input image stride
    const int OW = 256;           // output width
    const int OHW = 256 * 256;    // output image stride
    const long long N = 512LL * 256 * 256;  // per-subband element count

    for (int t = blockIdx.x * blockDim.x + threadIdx.x; t < total;
         t += gridDim.x * blockDim.x) {
        int jv = t & 127;
        int i = (t >> 7) & 255;
        int bc = t >> 15;

        long long base = (long long)bc * HW + (long long)(2 * i) * W + 4 * jv;
        float4 r0 = *reinterpret_cast<const float4*>(x + base);
        float4 r1 = *reinterpret_cast<const float4*>(x + base + W);

        float2 ll, lh, hl, hh;
        {
            float a = r0.x, b = r0.y, c = r1.x, d = r1.y;
            ll.x = 0.5f * (a + b + c + d);
            lh.x = 0.5f * (a - b + c - d);
            hl.x = 0.5f * (a + b - c - d);
            hh.x = 0.5f * (a - b - c + d);
        }
        {
            float a = r0.z, b = r0.w, c = r1.z, d = r1.w;
            ll.y = 0.5f * (a + b + c + d);
            lh.y = 0.5f * (a - b + c - d);
            hl.y = 0.5f * (a + b - c - d);
            hh.y = 0.5f * (a - b - c + d);
        }

        long long o = (long long)bc * OHW + (long long)i * OW + 2 * jv;
        *reinterpret_cast<float2*>(out + o) = ll;
        *reinterpret_cast<float2*>(out + N + o) = lh;
        *reinterpret_cast<float2*>(out + 2 * N + o) = hl;
        *reinterpret_cast<float2*>(out + 3 * N + o) = hh;
    }
}

extern "C" void kernel_launch(void* const* d_in, const int* in_sizes, int n_in,
                              void* d_out, int out_size, void* d_ws,
                              size_t ws_size, hipStream_t stream) {
    const float* x = (const float*)d_in[0];
    // d_in[1..4] are the dense Haar matrices; the butterfly supersedes them.
    float* out = (float*)d_out;

    const int total = 512 * 256 * 128;  // 16,777,216 work items
    const int block = 256;
    const int grid = 2048;  // 256 CU x 8 blocks/CU, grid-stride the rest
    haar_dwt_kernel<<<grid, block, 0, stream>>>(x, out, total);
}